// Round 3
// baseline (814.802 us; speedup 1.0000x reference)
//
#include <hip/hip_runtime.h>
#include <hip/hip_bf16.h>

#define T_STEPS 20
#define NSTEP   19
#define NN      192
#define DH      64
#define DE      32

// ---------------- workspace float offsets ----------------
enum : int {
  O_H     = 0,                 // committed h   [N][64]
  O_C     = O_H   + NN*DH,
  O_HW0   = O_C   + NN*DH,     // h entering gcn0 (LSTM out)
  O_HW1   = O_HW0 + NN*DH,     // h entering gcn1 (gcn0 out, all rows)
  O_CW    = O_HW1 + NN*DH,     // working c
  O_OG    = O_CW  + NN*DH,     // LSTM o-gate
  O_U1    = O_OG  + NN*DH,     // h_i-part of gate preact
  O_U20   = O_U1  + NN*DH,     // h_j-part, for gcn0
  O_U21   = O_U20 + NN*DH,     // h_j-part, for gcn1
  O_S1    = O_U21 + NN*DH,     // h_i-part of score
  O_S20   = O_S1  + NN,
  O_S21   = O_S20 + NN,
  O_ACC   = O_S21 + NN,        // [19][4]: sg, sn, sp, sm
  O_WIHT  = O_ACC + NSTEP*4 + 4,   // [e][G]  8192   (zeroed state region ends here)
  O_WHHT  = O_WIHT + 8192,         // [k][G]  16384
  O_BIH   = O_WHHT + 16384,        // 256 (b_ih+b_hh)
  O_WIN   = O_BIH  + 256,          // 64
  O_BIN   = O_WIN  + 64,           // 32
  O_WRELF = O_BIN  + 32,           // 128  [p][d][c]
  O_BRELF = O_WRELF+ 128,          // 64
  O_WGR   = O_BRELF+ 64,           // 4096 [p][h][d<32]
  O_WGH1T = O_WGR  + 4096,         // 8192 [p][k][h]
  O_WGH2T = O_WGH1T+ 8192,         // 8192
  O_BGATE = O_WGH2T+ 8192,         // 128
  O_WARR  = O_BGATE+ 128,          // 64  [p][d]
  O_WARH1 = O_WARR + 64,           // 128 [p][k]
  O_WARH2 = O_WARH1+ 128,          // 128
  O_BAR   = O_WARH2+ 128,          // 4 (2 used)
  O_WNEIT = O_BAR  + 4,            // 8192 [p][k][h]
  O_WOUT  = O_WNEIT+ 8192,         // 128 [o][h]
  O_BOUT  = O_WOUT + 128,          // 2
  O_FLAG  = O_BOUT + 2,            // dtype flag: 0 = bf16 inputs, 1 = float32
  O_TOTAL = O_FLAG + 1
};

__device__ __forceinline__ float bf2f(__hip_bfloat16 v) { return __bfloat162float(v); }
__device__ __forceinline__ float sigm(float x) { return 1.0f / (1.0f + expf(-x)); }

// dtype-flex load/store
__device__ __forceinline__ float ldf(const void* p, int idx, int isf32) {
  if (isf32) return ((const float*)p)[idx];
  return bf2f(((const __hip_bfloat16*)p)[idx]);
}
__device__ __forceinline__ void stf(void* p, int idx, float v, int isf32) {
  if (isf32) ((float*)p)[idx] = v;
  else       ((__hip_bfloat16*)p)[idx] = __float2bfloat16(v);
}

// ---------------- dtype detection from w_gate bit patterns ----------------
// bf16 data: every uint16 is a bf16 with |v| <= ~0.5 (sigma=0.1). float32 data:
// even uint16s are random mantissa bits -> ~49% decode as bf16 with |v|>4 or NaN.
__global__ void k_detect(float* __restrict__ F, const void* __restrict__ wgate) {
  const unsigned short* u = (const unsigned short*)wgate;
  int bad = 0;
  for (int x = threadIdx.x; x < 1024; x += 64) {
    unsigned int bits = ((unsigned int)u[x]) << 16;
    float v = __uint_as_float(bits);
    if (!(fabsf(v) <= 4.0f)) bad++;   // catches NaN too
  }
  for (int o = 32; o >= 1; o >>= 1) bad += __shfl_xor(bad, o, 64);
  if (threadIdx.x == 0) F[O_FLAG] = (bad > 64) ? 1.f : 0.f;
}

// ---------------- init: zero state, convert/transpose weights ----------------
__global__ void k_init(float* __restrict__ F,
                       const void* w_in,  const void* b_in,
                       const void* w_ih,  const void* w_hh,
                       const void* b_ih,  const void* b_hh,
                       const void* w_rel, const void* b_rel,
                       const void* w_gate,const void* b_gate,
                       const void* w_ar,  const void* b_ar,
                       const void* w_nei, const void* w_out,
                       const void* b_out,
                       void* __restrict__ out) {
  const int isf32 = (F[O_FLAG] != 0.f);
  int tid = blockIdx.x * blockDim.x + threadIdx.x;
  int stride = gridDim.x * blockDim.x;
  for (int x = tid; x < O_WIHT; x += stride) F[x] = 0.f;    // whole state region
  for (int x = tid; x < NN*2;  x += stride) stf(out, (T_STEPS-1)*NN*2 + x, 0.f, isf32);
  for (int x = tid; x < 8192;  x += stride) { int e = x >> 8, G = x & 255; F[O_WIHT + x] = ldf(w_ih, G*32 + e, isf32); }
  for (int x = tid; x < 16384; x += stride) { int k = x >> 8, G = x & 255; F[O_WHHT + x] = ldf(w_hh, G*64 + k, isf32); }
  for (int x = tid; x < 256;   x += stride) F[O_BIH + x] = ldf(b_ih, x, isf32) + ldf(b_hh, x, isf32);
  for (int x = tid; x < 64;    x += stride) F[O_WIN + x] = ldf(w_in, x, isf32);
  for (int x = tid; x < 32;    x += stride) F[O_BIN + x] = ldf(b_in, x, isf32);
  for (int x = tid; x < 128;   x += stride) F[O_WRELF + x] = ldf(w_rel, x, isf32);
  for (int x = tid; x < 64;    x += stride) F[O_BRELF + x] = ldf(b_rel, x, isf32);
  for (int x = tid; x < 4096;  x += stride) { int p = x >> 11, h = (x >> 5) & 63, d = x & 31;
    F[O_WGR + x] = ldf(w_gate, p*10240 + h*160 + d, isf32); }
  for (int x = tid; x < 8192;  x += stride) { int p = x >> 12, k = (x >> 6) & 63, h = x & 63;
    F[O_WGH1T + x] = ldf(w_gate, p*10240 + h*160 + 32 + k, isf32); }
  for (int x = tid; x < 8192;  x += stride) { int p = x >> 12, k = (x >> 6) & 63, h = x & 63;
    F[O_WGH2T + x] = ldf(w_gate, p*10240 + h*160 + 96 + k, isf32); }
  for (int x = tid; x < 128;   x += stride) F[O_BGATE + x] = ldf(b_gate, x, isf32);
  for (int x = tid; x < 64;    x += stride) { int p = x >> 5, d = x & 31; F[O_WARR + x] = ldf(w_ar, p*160 + d, isf32); }
  for (int x = tid; x < 128;   x += stride) { int p = x >> 6, k = x & 63; F[O_WARH1 + x] = ldf(w_ar, p*160 + 32 + k, isf32); }
  for (int x = tid; x < 128;   x += stride) { int p = x >> 6, k = x & 63; F[O_WARH2 + x] = ldf(w_ar, p*160 + 96 + k, isf32); }
  for (int x = tid; x < 2;     x += stride) F[O_BAR + x] = ldf(b_ar, x, isf32);
  for (int x = tid; x < 8192;  x += stride) { int p = x >> 12, k = (x >> 6) & 63, h = x & 63;
    F[O_WNEIT + x] = ldf(w_nei, p*4096 + h*64 + k, isf32); }
  for (int x = tid; x < 128;   x += stride) F[O_WOUT + x] = ldf(w_out, x, isf32);
  for (int x = tid; x < 2;     x += stride) F[O_BOUT + x] = ldf(b_out, x, isf32);
}

// ---------------- LSTM for step t (reads committed H/C) + prep for gcn0 ----------------
__global__ __launch_bounds__(256) void k_lstm(float* __restrict__ F,
                                              const void* __restrict__ nnorm,
                                              int t) {
  __shared__ float s_x[DE], s_h[DH], s_c[DH], s_gates[4*DH], s_h1[DH];
  const int tid = threadIdx.x, wave = tid >> 6, lane = tid & 63;
  const int i = blockIdx.x;
  const int isf32 = (F[O_FLAG] != 0.f);

  if (wave == 0) { s_h[lane] = F[O_H + i*DH + lane]; s_c[lane] = F[O_C + i*DH + lane]; }
  if (wave == 1 && lane < DE) {
    float nx = ldf(nnorm, (t*NN + i)*2 + 0, isf32);
    float ny = ldf(nnorm, (t*NN + i)*2 + 1, isf32);
    s_x[lane] = fmaxf(nx*F[O_WIN + lane*2] + ny*F[O_WIN + lane*2 + 1] + F[O_BIN + lane], 0.f);
  }
  __syncthreads();
  {
    int G = tid;                                   // gate-major: i,f,g,o
    float acc = F[O_BIH + G];
    for (int e = 0; e < DE; e++) acc += F[O_WIHT + e*256 + G] * s_x[e];
    for (int k = 0; k < DH; k++) acc += F[O_WHHT + k*256 + G] * s_h[k];
    s_gates[G] = acc;
  }
  __syncthreads();
  if (wave == 0) {
    float ig = sigm(s_gates[lane]);
    float fg = sigm(s_gates[64 + lane]);
    float gg = tanhf(s_gates[128 + lane]);
    float og = sigm(s_gates[192 + lane]);
    float c1 = fg * s_c[lane] + ig * gg;
    float h1 = og * tanhf(c1);
    int idx = i*DH + lane;
    F[O_CW  + idx] = c1;
    F[O_HW0 + idx] = h1;
    F[O_OG  + idx] = og;
    s_h1[lane] = h1;
  }
  __syncthreads();
  // PREP for gcn p=0: U1, U20, S1, S20
  {
    int idx = i*DH + lane;
    if (wave == 0) {
      float a = 0.f;
      const float* w = F + O_WGH1T + lane;         // p=0
      for (int k = 0; k < DH; k++) a += w[k*DH] * s_h1[k];
      F[O_U1 + idx] = a;
    } else if (wave == 1) {
      float a = 0.f;
      const float* w = F + O_WGH2T + lane;         // p=0
      for (int k = 0; k < DH; k++) a += w[k*DH] * s_h1[k];
      F[O_U20 + idx] = a;
    } else if (wave == 2) {
      float hp = s_h1[lane];
      float a1 = hp * F[O_WARH1 + lane];           // p=0
      float a2 = hp * F[O_WARH2 + lane];
      for (int o = 32; o >= 1; o >>= 1) {
        a1 += __shfl_xor(a1, o, 64);
        a2 += __shfl_xor(a2, o, 64);
      }
      if (lane == 0) { F[O_S1 + i] = a1; F[O_S20 + i] = a2; }
    }
  }
}

// ---------------- GCN pass p for step t ----------------
__global__ __launch_bounds__(256) void k_gcn(float* __restrict__ F,
                                             const void* __restrict__ nabs,
                                             const int* __restrict__ seq,
                                             const int* __restrict__ nei,
                                             void* __restrict__ out,
                                             int t, int p) {
  __shared__ float s_r[32*NN];                     // [d][j]
  __shared__ float s_score[NN], s_pos[NN], s_neif[NN];
  __shared__ float s_red[4*DH], s_v1[4], s_msg[DH], s_hprep[DH];

  const int tid = threadIdx.x, wave = tid >> 6, lane = tid & 63;
  const int i = blockIdx.x;
  const int isf32 = (F[O_FLAG] != 0.f);
  const int m_i = seq[t*NN + i] > 0;
  const int HWr = p ? O_HW1 : O_HW0;
  const int U2r = p ? O_U21 : O_U20;
  const int S2r = p ? O_S21 : O_S20;

  // ---- P1: mask, r values, raw scores
  if (wave < 3) {
    int j  = wave*64 + lane;
    int nf = m_i && (seq[t*NN + j] > 0) && (nei[(t*NN + i)*NN + j] > 0);
    s_neif[j] = nf ? 1.f : 0.f;
    float sc = 0.f;
    if (nf) {
      float cx = ldf(nabs, (t*NN + i)*2 + 0, isf32) - ldf(nabs, (t*NN + j)*2 + 0, isf32);
      float cy = ldf(nabs, (t*NN + i)*2 + 1, isf32) - ldf(nabs, (t*NN + j)*2 + 1, isf32);
      const float* wr = F + O_WRELF + p*64;
      const float* br = F + O_BRELF + p*32;
      const float* wa = F + O_WARR  + p*32;
      float dot = 0.f;
      for (int d = 0; d < 32; d++) {
        float rv = fmaxf(cx*wr[2*d] + cy*wr[2*d+1] + br[d], 0.f);
        s_r[d*NN + j] = rv;
        dot += rv * wa[d];
      }
      sc = dot + F[O_S1 + i] + F[S2r + j] + F[O_BAR + p];
    }
    s_score[j] = sc;
  }
  __syncthreads();

  // ---- P2: masked softmax with explicit validity (wave 0)
  if (wave == 0) {
    float n0 = s_neif[lane], n1 = s_neif[64+lane], n2 = s_neif[128+lane];
    float sc0 = s_score[lane], sc1 = s_score[64+lane], sc2 = s_score[128+lane];
    const float NEG = -3.0e38f;
    float mx = fmaxf(fmaxf(n0 > 0.f ? sc0 : NEG, n1 > 0.f ? sc1 : NEG),
                     n2 > 0.f ? sc2 : NEG);
    for (int o = 32; o >= 1; o >>= 1) mx = fmaxf(mx, __shfl_xor(mx, o, 64));
    float e0 = (n0 > 0.f) ? expf(sc0 - mx) : 0.f;
    float e1 = (n1 > 0.f) ? expf(sc1 - mx) : 0.f;
    float e2 = (n2 > 0.f) ? expf(sc2 - mx) : 0.f;
    float s = e0 + e1 + e2;
    for (int o = 32; o >= 1; o >>= 1) s += __shfl_xor(s, o, 64);
    float inv = (s > 0.f) ? 1.0f / s : 0.f;
    float p0 = e0*inv, p1 = e1*inv, p2 = e2*inv;
    s_pos[lane] = p0; s_pos[64+lane] = p1; s_pos[128+lane] = p2;
    if (p == 0 && m_i) {
      float cnt = n0 + n1 + n2;
      float pm  = fmaxf(fmaxf(p0, p1), p2);
      for (int o = 32; o >= 1; o >>= 1) {
        cnt += __shfl_xor(cnt, o, 64);
        pm   = fmaxf(pm, __shfl_xor(pm, o, 64));
      }
      if (lane == 0 && cnt > 0.f) {
        atomicAdd(&F[O_ACC + t*4 + 1], cnt);   // sum nei_f
        atomicAdd(&F[O_ACC + t*4 + 2], pm);    // sum_i max_j pos
        atomicAdd(&F[O_ACC + t*4 + 3], 1.f);   // sum_i max_j nei_f
      }
    }
  }
  __syncthreads();

  // ---- P3: gates + msg partials (all waves; lane = h, j strided by wave)
  {
    float msg = 0.f, v1 = 0.f;
    if (m_i) {
      float wreg[32];
      const float* wg = F + O_WGR + p*2048 + lane*32;
      for (int d = 0; d < 32; d++) wreg[d] = wg[d];
      float base = F[O_U1 + i*DH + lane] + F[O_BGATE + p*DH + lane];
      for (int j = wave; j < NN; j += 4) {
        if (s_neif[j] == 0.f) continue;        // wave-uniform (same j per wave)
        float acc = base + F[U2r + j*DH + lane];
        for (int d = 0; d < 32; d++) acc += s_r[d*NN + j] * wreg[d];
        float g = 1.0f / (1.0f + expf(-acc));
        v1 += g;
        msg += s_pos[j] * g * F[HWr + j*DH + lane];
      }
    }
    s_red[wave*DH + lane] = msg;
    for (int o = 32; o >= 1; o >>= 1) v1 += __shfl_xor(v1, o, 64);
    if (lane == 0) s_v1[wave] = v1;
  }
  __syncthreads();

  // ---- T1: combine msg partials + v1 atomic (wave 0)
  if (wave == 0) {
    s_msg[lane] = s_red[lane] + s_red[64+lane] + s_red[128+lane] + s_red[192+lane];
    if (p == 0 && m_i && lane == 0) {
      float v1t = s_v1[0] + s_v1[1] + s_v1[2] + s_v1[3];
      atomicAdd(&F[O_ACC + t*4 + 0], v1t);
    }
  }
  __syncthreads();

  // ---- T2: c/h update; publish (p=0) or commit (p=1)
  if (wave == 0) {
    int idx = i*DH + lane;
    float hcom;
    if (m_i) {
      float cn = F[O_CW + idx];
      const float* wn = F + O_WNEIT + p*4096 + lane;
      for (int k = 0; k < DH; k++) cn += s_msg[k] * wn[k*DH];
      hcom = F[O_OG + idx] * tanhf(cn);
      F[O_CW + idx] = cn;
      if (p == 1) { F[O_H + idx] = hcom; F[O_C + idx] = cn; }
    } else {
      hcom = F[HWr + idx];                     // gcn is identity for masked rows
    }
    if (p == 0) F[O_HW1 + idx] = hcom;         // unconditional publish, all rows
    s_hprep[lane] = hcom;
  }
  __syncthreads();

  // ---- OUT (p==1)
  if (p == 1 && wave == 0 && lane < 2) {
    float a = 0.f;
    if (m_i) {
      a = F[O_BOUT + lane];
      const float* wo = F + O_WOUT + lane*DH;
      for (int h = 0; h < DH; h++) a += s_hprep[h] * wo[h];
    }
    stf(out, (t*NN + i)*2 + lane, a, isf32);
  }

  // ---- PREP (p==0): U1/U21/S1/S21 for the p=1 pass, from post-gcn0 h
  if (p == 0) {
    int idx = i*DH + lane;
    if (wave == 0) {
      float a = 0.f;
      const float* w = F + O_WGH1T + 4096 + lane;  // p=1
      for (int k = 0; k < DH; k++) a += w[k*DH] * s_hprep[k];
      F[O_U1 + idx] = a;
    } else if (wave == 1) {
      float a = 0.f;
      const float* w = F + O_WGH2T + 4096 + lane;  // p=1
      for (int k = 0; k < DH; k++) a += w[k*DH] * s_hprep[k];
      F[O_U21 + idx] = a;
    } else if (wave == 2) {
      float hp = s_hprep[lane];
      float a1 = hp * F[O_WARH1 + DH + lane];      // p=1
      float a2 = hp * F[O_WARH2 + DH + lane];
      for (int o = 32; o >= 1; o >>= 1) {
        a1 += __shfl_xor(a1, o, 64);
        a2 += __shfl_xor(a2, o, 64);
      }
      if (lane == 0) { F[O_S1 + i] = a1; F[O_S21 + i] = a2; }
    }
  }
}

// ---------------- finalize: h, c, scalars ----------------
__global__ void k_fin(const float* __restrict__ F, void* __restrict__ out) {
  const int isf32 = (F[O_FLAG] != 0.f);
  int tid = blockIdx.x * blockDim.x + threadIdx.x;
  int stride = gridDim.x * blockDim.x;
  for (int x = tid; x < NN*DH; x += stride) stf(out, T_STEPS*NN*2 + x,          F[O_H + x], isf32);
  for (int x = tid; x < NN*DH; x += stride) stf(out, T_STEPS*NN*2 + NN*DH + x,  F[O_C + x], isf32);
  if (blockIdx.x == 0 && threadIdx.x == 0) {
    float v1 = 0.f, v2 = 0.f, v3 = 0.f;
    for (int t = 0; t < NSTEP; t++) {
      float sg = F[O_ACC + t*4 + 0], sn = F[O_ACC + t*4 + 1];
      float sp = F[O_ACC + t*4 + 2], sm = F[O_ACC + t*4 + 3];
      v1 += sg / (sn * 64.f + 1e-6f);
      v2 += sp / (sm + 1e-6f);
      v3 += sn / 192.f;
    }
    int base = T_STEPS*NN*2 + 2*NN*DH;
    stf(out, base + 0, v1 / 20.f, isf32);
    stf(out, base + 1, v2 / 20.f, isf32);
    stf(out, base + 2, v3 / 20.f, isf32);
  }
}

extern "C" void kernel_launch(void* const* d_in, const int* in_sizes, int n_in,
                              void* d_out, int out_size, void* d_ws, size_t ws_size,
                              hipStream_t stream) {
  const void* nodes_abs  = d_in[0];
  const void* nodes_norm = d_in[1];
  const void* w_in   = d_in[3];
  const void* b_in   = d_in[4];
  const void* w_ih   = d_in[5];
  const void* w_hh   = d_in[6];
  const void* b_ih   = d_in[7];
  const void* b_hh   = d_in[8];
  const void* w_rel  = d_in[9];
  const void* b_rel  = d_in[10];
  const void* w_gate = d_in[11];
  const void* b_gate = d_in[12];
  const void* w_ar   = d_in[13];
  const void* b_ar   = d_in[14];
  const void* w_nei  = d_in[15];
  const void* w_out  = d_in[16];
  const void* b_out  = d_in[17];
  const int* seq = (const int*)d_in[18];
  const int* nei = (const int*)d_in[19];
  float* F = (float*)d_ws;

  k_detect<<<1, 64, 0, stream>>>(F, w_gate);
  k_init<<<128, 256, 0, stream>>>(F, w_in, b_in, w_ih, w_hh, b_ih, b_hh, w_rel, b_rel,
                                  w_gate, b_gate, w_ar, b_ar, w_nei, w_out, b_out, d_out);
  for (int t = 0; t < NSTEP; t++) {
    k_lstm<<<NN, 256, 0, stream>>>(F, nodes_norm, t);
    k_gcn <<<NN, 256, 0, stream>>>(F, nodes_abs, seq, nei, d_out, t, 0);
    k_gcn <<<NN, 256, 0, stream>>>(F, nodes_abs, seq, nei, d_out, t, 1);
  }
  k_fin<<<48, 256, 0, stream>>>(F, d_out);
}